// Round 1
// baseline (347.832 us; speedup 1.0000x reference)
//
#include <hip/hip_runtime.h>
#include <hip/hip_bf16.h>

typedef _Float16 f16;
typedef f16 f16x2 __attribute__((ext_vector_type(2)));
typedef f16 f16x4 __attribute__((ext_vector_type(4)));
typedef f16 f16x8 __attribute__((ext_vector_type(8)));
typedef float f32x4 __attribute__((ext_vector_type(4)));

#define MFMA16(a, b, c) __builtin_amdgcn_mfma_f32_16x16x32_f16(a, b, c, 0, 0, 0)

__device__ __forceinline__ void glds16(const void* g, void* l) {
    __builtin_amdgcn_global_load_lds(
        (const __attribute__((address_space(1))) unsigned int*)g,
        (__attribute__((address_space(3))) unsigned int*)l, 16, 0, 0);
}

// ---------------- f32 -> f16 convert ----------------
__global__ __launch_bounds__(256) void cvt_kernel(const float* __restrict__ s,
                                                  f16* __restrict__ d, int n) {
    int i = (blockIdx.x * 256 + threadIdx.x) * 8;
    if (i >= n) return;
    float4 a = *(const float4*)(s + i);
    float4 b = *(const float4*)(s + i + 4);
    f16x8 h;
    h[0] = (f16)a.x; h[1] = (f16)a.y; h[2] = (f16)a.z; h[3] = (f16)a.w;
    h[4] = (f16)b.x; h[5] = (f16)b.y; h[6] = (f16)b.z; h[7] = (f16)b.w;
    *(f16x8*)(d + i) = h;
}

// ---------------- GEMM: C[M,N] = A[M,K] @ B[N,K]^T + bias ----------------
// 128x128 tile, BK=32, 4 waves (2x2), each wave 64x64 (4x4 mfma tiles)
template <bool A_F32, bool OUT_F16>
__global__ __launch_bounds__(256) void gemm_bt_kernel(
    const void* __restrict__ A_, const f16* __restrict__ Bw,
    const float* __restrict__ bias, void* __restrict__ C_, int M, int N, int K) {
    __shared__ f16 As[128 * 32];
    __shared__ f16 Bs[128 * 32];
    const int tid = threadIdx.x;
    const int lane = tid & 63;
    const int w = tid >> 6;
    const int nblk = N >> 7;
    const int mb = (int)blockIdx.x / nblk, nb = (int)blockIdx.x % nblk;
    const int wm = w >> 1, wn = w & 1;
    const int q = lane >> 4, cl = lane & 15;

    const f16* Bbase = Bw + (size_t)nb * 128 * K;
    const float* A32 = (const float*)A_;
    const f16* A16 = (const f16*)A_;

    f32x4 acc[4][4] = {};

#pragma unroll 1
    for (int kt = 0; kt < (K >> 5); ++kt) {
        const int k0 = kt << 5;
        // stage B via global_load_lds (16B/lane), LDS [128][32] f16 linear
#pragma unroll
        for (int it = 0; it < 2; ++it) {
            int c = it * 256 + w * 64 + lane;
            glds16(Bbase + (size_t)(c >> 2) * K + k0 + (c & 3) * 8,
                   &Bs[(it * 256 + w * 64) * 8]);
        }
        if (A_F32) {
            // reg-stage with f32->f16 convert
#pragma unroll
            for (int it = 0; it < 2; ++it) {
                int c = tid + it * 256;
                int row = c >> 2, kc = c & 3;
                const float* sp = A32 + (size_t)(mb * 128 + row) * K + k0 + kc * 8;
                float4 a = *(const float4*)sp;
                float4 b = *(const float4*)(sp + 4);
                f16x8 h;
                h[0] = (f16)a.x; h[1] = (f16)a.y; h[2] = (f16)a.z; h[3] = (f16)a.w;
                h[4] = (f16)b.x; h[5] = (f16)b.y; h[6] = (f16)b.z; h[7] = (f16)b.w;
                *(f16x8*)&As[c * 8] = h;
            }
        } else {
#pragma unroll
            for (int it = 0; it < 2; ++it) {
                int c = it * 256 + w * 64 + lane;
                glds16(A16 + (size_t)(mb * 128 + (c >> 2)) * K + k0 + (c & 3) * 8,
                       &As[(it * 256 + w * 64) * 8]);
            }
        }
        __syncthreads();
        f16x8 af[4], bf[4];
#pragma unroll
        for (int mt = 0; mt < 4; ++mt)
            af[mt] = *(const f16x8*)&As[(wm * 64 + mt * 16 + cl) * 32 + q * 8];
#pragma unroll
        for (int nt = 0; nt < 4; ++nt)
            bf[nt] = *(const f16x8*)&Bs[(wn * 64 + nt * 16 + cl) * 32 + q * 8];
#pragma unroll
        for (int mt = 0; mt < 4; ++mt)
#pragma unroll
            for (int nt = 0; nt < 4; ++nt)
                acc[mt][nt] = MFMA16(af[mt], bf[nt], acc[mt][nt]);
        __syncthreads();
    }
    // epilogue: C row = (lane>>4)*4+reg, col = lane&15 within each 16x16 tile
    float bv[4];
#pragma unroll
    for (int nt = 0; nt < 4; ++nt) bv[nt] = bias[nb * 128 + wn * 64 + nt * 16 + cl];
#pragma unroll
    for (int mt = 0; mt < 4; ++mt) {
#pragma unroll
        for (int nt = 0; nt < 4; ++nt) {
            size_t gr = (size_t)(mb * 128 + wm * 64 + mt * 16 + q * 4);
            int gc = nb * 128 + wn * 64 + nt * 16 + cl;
#pragma unroll
            for (int r = 0; r < 4; ++r) {
                float v = acc[mt][nt][r] + bv[nt];
                if (OUT_F16)
                    ((f16*)C_)[(gr + r) * N + gc] = (f16)v;
                else
                    ((float*)C_)[(gr + r) * N + gc] = v;
            }
        }
    }
}

// ---------------- segment-average partials ----------------
// partial[bn][rc][c] = (1/256) * sum over 64 rows of X1h[bn*256 + rc*64 + l][c]
__global__ __launch_bounds__(256) void avg_kernel(const f16* __restrict__ X1h,
                                                  float* __restrict__ partial) {
    const int bn = blockIdx.x >> 2, rc = blockIdx.x & 3;
    const int tid = threadIdx.x;
    const f16* base = X1h + (size_t)bn * 262144 + (size_t)rc * 65536 + tid * 4;
    float s0 = 0.f, s1 = 0.f, s2 = 0.f, s3 = 0.f;
    for (int l = 0; l < 64; ++l) {
        f16x4 v = *(const f16x4*)(base + (size_t)l * 1024);
        s0 += (float)v[0]; s1 += (float)v[1]; s2 += (float)v[2]; s3 += (float)v[3];
    }
    const float sc = 1.f / 256.f;
    float4 o = make_float4(s0 * sc, s1 * sc, s2 * sc, s3 * sc);
    *(float4*)(partial + (size_t)(bn * 4 + rc) * 1024 + tid * 4) = o;
}

// ---------------- router: logits + softmax over E=16 ----------------
__global__ __launch_bounds__(64) void router_kernel(const float* __restrict__ partial,
                                                    const float* __restrict__ emb,
                                                    float* __restrict__ ew) {
    const int t = blockIdx.x;  // (b*16+n)*8 + h
    const int bn = t >> 3, h = t & 7;
    const int lane = threadIdx.x;
    float acc = 0.f;
    const float* p = partial + (size_t)bn * 4096 + h * 128;
    if (lane < 16) {
        for (int d = 0; d < 128; ++d) {
            float a = p[d] + p[d + 1024] + p[d + 2048] + p[d + 3072];
            acc = fmaf(a, emb[d * 16 + lane], acc);
        }
    }
    float m = acc;
#pragma unroll
    for (int o = 8; o; o >>= 1) m = fmaxf(m, __shfl_xor(m, o));
    float pr = __expf(acc - m);
    float s = pr;
#pragma unroll
    for (int o = 8; o; o >>= 1) s += __shfl_xor(s, o);
    if (lane < 16) ew[t * 16 + lane] = pr / s;
}

// ---------------- expert mixture: m{1,2}h[t] = sum_e ew[t,e]*{FL,SL}[e] ----------------
__global__ __launch_bounds__(256) void mix_kernel(const float* __restrict__ ew,
                                                  const float* __restrict__ FL,
                                                  const float* __restrict__ SL,
                                                  f16* __restrict__ m1h,
                                                  f16* __restrict__ m2h) {
    __shared__ float ews[4096];
    const int bid = blockIdx.x;
    const int which = bid >> 8, th = (bid >> 7) & 1, chunk = bid & 127;
    const float* src = which ? SL : FL;
    f16* dst = which ? m2h : m1h;
    const int tid = threadIdx.x;
    const int e0 = chunk * 512 + tid * 2;
    float2 fl[16];
#pragma unroll
    for (int e = 0; e < 16; ++e)
        fl[e] = *(const float2*)(src + (size_t)e * 65536 + e0);
    for (int i = tid; i < 4096; i += 256) ews[i] = ew[th * 4096 + i];
    __syncthreads();
#pragma unroll 1
    for (int tt = 0; tt < 256; ++tt) {
        float a0 = 0.f, a1 = 0.f;
#pragma unroll
        for (int e = 0; e < 16; ++e) {
            float wgt = ews[tt * 16 + e];
            a0 = fmaf(wgt, fl[e].x, a0);
            a1 = fmaf(wgt, fl[e].y, a1);
        }
        f16x2 h;
        h[0] = (f16)a0; h[1] = (f16)a1;
        *(f16x2*)(dst + (size_t)(th * 256 + tt) * 65536 + e0) = h;
    }
}

// ---------------- MLP: Y = relu(X @ m1^T) @ m2^T per (tile, half) ----------------
// block = 256 thr / 4 waves; wave owns 32 l-rows end-to-end (no inner barriers).
// stage1 computes h^T (A=m1, B=X) so relu output packs as contiguous ds_write_b64
// into Hs[l][i]; stage2 consumes Hs rows as A-operand. LDS XOR-swizzled (stride 256B).
__global__ __launch_bounds__(256) void mlp_kernel(const f16* __restrict__ Xg,
                                                  const f16* __restrict__ m1h,
                                                  const f16* __restrict__ m2h,
                                                  f16* __restrict__ Yg) {
    __shared__ f16 Xs[128 * 128];
    __shared__ f16 Hs[128 * 128];
    const int bid = blockIdx.x;
    const int t = bid >> 1, lh = bid & 1;
    const int n = (t >> 3) & 15;
    const int tm = (n > 0) ? (t - 8) : t;
    const int tid = threadIdx.x;
    const int lane = tid & 63, w = tid >> 6;
    const int q = lane >> 4, cl = lane & 15;

    // stage X half-tile (contiguous 32KB), pre-swizzled source for linear glds dest
    const f16* Xsrc = Xg + (size_t)t * 32768 + lh * 16384;
#pragma unroll
    for (int it = 0; it < 8; ++it) {
        int cbase = it * 256 + w * 64;
        int c = cbase + lane;
        int row = c >> 4, pc = c & 15;
        int lc = pc ^ (row & 7);
        glds16(Xsrc + row * 128 + lc * 8, &Xs[cbase * 8]);
    }
    const f16* m1b = m1h + (size_t)tm * 65536;
    const f16* m2b = m2h + (size_t)tm * 65536;
    f32x4 acc2[2][8] = {};
    __syncthreads();

    const int l0 = w * 32;
#pragma unroll 1
    for (int ic = 0; ic < 4; ++ic) {
        // ---- stage1: h^T[i, l] for wave's 32 l, i in [ic*128, ic*128+128) ----
        f16x8 xf[2][4];
#pragma unroll
        for (int lt = 0; lt < 2; ++lt) {
            int l = l0 + lt * 16 + cl;
#pragma unroll
            for (int ks = 0; ks < 4; ++ks) {
                int ch = (ks * 4 + q) ^ (l & 7);
                xf[lt][ks] = *(const f16x8*)&Xs[l * 128 + ch * 8];
            }
        }
#pragma unroll
        for (int it = 0; it < 8; ++it) {
            f16x8 af[4];
#pragma unroll
            for (int ks = 0; ks < 4; ++ks)
                af[ks] = *(const f16x8*)(m1b + (size_t)(ic * 128 + it * 16 + cl) * 128 +
                                         ks * 32 + q * 8);
            f32x4 a1[2] = {};
#pragma unroll
            for (int ks = 0; ks < 4; ++ks)
#pragma unroll
                for (int lt = 0; lt < 2; ++lt)
                    a1[lt] = MFMA16(af[ks], xf[lt][ks], a1[lt]);
            // relu + pack 4 consecutive i into one b64 write to Hs[l][i] (swizzled)
            int ibase = it * 16 + q * 4;
            int ch = ibase >> 3;
            int sub = (q & 1) * 8;
#pragma unroll
            for (int lt = 0; lt < 2; ++lt) {
                int l = l0 + lt * 16 + cl;
                f16x4 hv;
                hv[0] = (f16)fmaxf(a1[lt][0], 0.f);
                hv[1] = (f16)fmaxf(a1[lt][1], 0.f);
                hv[2] = (f16)fmaxf(a1[lt][2], 0.f);
                hv[3] = (f16)fmaxf(a1[lt][3], 0.f);
                *(f16x4*)((char*)Hs + (size_t)l * 256 + ((ch ^ (l & 7)) << 4) + sub) = hv;
            }
        }
        // ---- stage2: acc2 += h[l, :] @ m2[:, ic-chunk]^T (same-wave LDS dep) ----
        f16x8 hf[2][4];
#pragma unroll
        for (int lt = 0; lt < 2; ++lt) {
            int l = l0 + lt * 16 + cl;
#pragma unroll
            for (int ks = 0; ks < 4; ++ks) {
                int ch = (ks * 4 + q) ^ (l & 7);
                hf[lt][ks] = *(const f16x8*)&Hs[l * 128 + ch * 8];
            }
        }
#pragma unroll
        for (int nt = 0; nt < 8; ++nt) {
            f16x8 bf[4];
#pragma unroll
            for (int ks = 0; ks < 4; ++ks)
                bf[ks] = *(const f16x8*)(m2b + (size_t)(nt * 16 + cl) * 512 + ic * 128 +
                                         ks * 32 + q * 8);
#pragma unroll
            for (int lt = 0; lt < 2; ++lt)
#pragma unroll
                for (int ks = 0; ks < 4; ++ks)
                    acc2[lt][nt] = MFMA16(hf[lt][ks], bf[ks], acc2[lt][nt]);
        }
    }
    // epilogue: Y[l][d] (in-place over X region is safe: X fully in LDS)
    f16* Yb = Yg + (size_t)t * 32768 + lh * 16384;
#pragma unroll
    for (int lt = 0; lt < 2; ++lt) {
#pragma unroll
        for (int nt = 0; nt < 8; ++nt) {
            int lr = l0 + lt * 16 + q * 4;
            int d = nt * 16 + cl;
#pragma unroll
            for (int r = 0; r < 4; ++r)
                Yb[(size_t)(lr + r) * 128 + d] = (f16)acc2[lt][nt][r];
        }
    }
}

extern "C" void kernel_launch(void* const* d_in, const int* in_sizes, int n_in,
                              void* d_out, int out_size, void* d_ws, size_t ws_size,
                              hipStream_t stream) {
    const float* x    = (const float*)d_in[0];
    const float* W_mh = (const float*)d_in[1];
    const float* b_mh = (const float*)d_in[2];
    const float* W_mg = (const float*)d_in[3];
    const float* b_mg = (const float*)d_in[4];
    const float* emb  = (const float*)d_in[5];
    const float* FL   = (const float*)d_in[6];
    const float* SL   = (const float*)d_in[7];

    char* ws = (char*)d_ws;
    f16*   X1h  = (f16*)(ws + 0);          // 33,554,432 B (doubles as Y, in-place)
    f16*   m1h  = (f16*)(ws + 33554432);   // 67,108,864 B
    f16*   m2h  = (f16*)(ws + 100663296);  // 67,108,864 B
    f16*   Wmhh = (f16*)(ws + 167772160);  // 2,097,152 B
    f16*   Wmgh = (f16*)(ws + 169869312);  // 2,097,152 B
    float* part = (float*)(ws + 171966464);// 1,048,576 B
    float* ew   = (float*)(ws + 173015040);// 32,768 B

    cvt_kernel<<<512, 256, 0, stream>>>(W_mh, Wmhh, 1048576);
    cvt_kernel<<<512, 256, 0, stream>>>(W_mg, Wmgh, 1048576);
    gemm_bt_kernel<true, true><<<1024, 256, 0, stream>>>(x, Wmhh, b_mh, X1h,
                                                         16384, 1024, 1024);
    avg_kernel<<<256, 256, 0, stream>>>(X1h, part);
    router_kernel<<<512, 64, 0, stream>>>(part, emb, ew);
    mix_kernel<<<512, 256, 0, stream>>>(ew, FL, SL, m1h, m2h);
    mlp_kernel<<<1024, 256, 0, stream>>>(X1h, m1h, m2h, X1h);
    gemm_bt_kernel<false, false><<<1024, 256, 0, stream>>>(X1h, Wmgh, b_mg, d_out,
                                                           16384, 1024, 1024);
}

// Round 2
// 275.508 us; speedup vs baseline: 1.2625x; 1.2625x over previous
//
#include <hip/hip_runtime.h>
#include <hip/hip_bf16.h>

typedef _Float16 f16;
typedef f16 f16x2 __attribute__((ext_vector_type(2)));
typedef f16 f16x4 __attribute__((ext_vector_type(4)));
typedef f16 f16x8 __attribute__((ext_vector_type(8)));
typedef float f32x4 __attribute__((ext_vector_type(4)));

#define MFMA16(a, b, c) __builtin_amdgcn_mfma_f32_16x16x32_f16(a, b, c, 0, 0, 0)

__device__ __forceinline__ void glds16(const void* g, void* l) {
    __builtin_amdgcn_global_load_lds(
        (const __attribute__((address_space(1))) unsigned int*)g,
        (__attribute__((address_space(3))) unsigned int*)l, 16, 0, 0);
}

// ---------------- f32 -> f16 convert ----------------
__global__ __launch_bounds__(256) void cvt_kernel(const float* __restrict__ s,
                                                  f16* __restrict__ d, int n) {
    int i = (blockIdx.x * 256 + threadIdx.x) * 8;
    if (i >= n) return;
    float4 a = *(const float4*)(s + i);
    float4 b = *(const float4*)(s + i + 4);
    f16x8 h;
    h[0] = (f16)a.x; h[1] = (f16)a.y; h[2] = (f16)a.z; h[3] = (f16)a.w;
    h[4] = (f16)b.x; h[5] = (f16)b.y; h[6] = (f16)b.z; h[7] = (f16)b.w;
    *(f16x8*)(d + i) = h;
}

// ---------------- GEMM: C[M,N] = A[M,K] @ B[N,K]^T + bias ----------------
template <bool A_F32, bool OUT_F16>
__global__ __launch_bounds__(256) void gemm_bt_kernel(
    const void* __restrict__ A_, const f16* __restrict__ Bw,
    const float* __restrict__ bias, void* __restrict__ C_, int M, int N, int K) {
    __shared__ f16 As[128 * 32];
    __shared__ f16 Bs[128 * 32];
    const int tid = threadIdx.x;
    const int lane = tid & 63;
    const int w = tid >> 6;
    const int nblk = N >> 7;
    const int mb = (int)blockIdx.x / nblk, nb = (int)blockIdx.x % nblk;
    const int wm = w >> 1, wn = w & 1;
    const int q = lane >> 4, cl = lane & 15;

    const f16* Bbase = Bw + (size_t)nb * 128 * K;
    const float* A32 = (const float*)A_;
    const f16* A16 = (const f16*)A_;

    f32x4 acc[4][4] = {};

#pragma unroll 1
    for (int kt = 0; kt < (K >> 5); ++kt) {
        const int k0 = kt << 5;
#pragma unroll
        for (int it = 0; it < 2; ++it) {
            int c = it * 256 + w * 64 + lane;
            glds16(Bbase + (size_t)(c >> 2) * K + k0 + (c & 3) * 8,
                   &Bs[(it * 256 + w * 64) * 8]);
        }
        if (A_F32) {
#pragma unroll
            for (int it = 0; it < 2; ++it) {
                int c = tid + it * 256;
                int row = c >> 2, kc = c & 3;
                const float* sp = A32 + (size_t)(mb * 128 + row) * K + k0 + kc * 8;
                float4 a = *(const float4*)sp;
                float4 b = *(const float4*)(sp + 4);
                f16x8 h;
                h[0] = (f16)a.x; h[1] = (f16)a.y; h[2] = (f16)a.z; h[3] = (f16)a.w;
                h[4] = (f16)b.x; h[5] = (f16)b.y; h[6] = (f16)b.z; h[7] = (f16)b.w;
                *(f16x8*)&As[c * 8] = h;
            }
        } else {
#pragma unroll
            for (int it = 0; it < 2; ++it) {
                int c = it * 256 + w * 64 + lane;
                glds16(A16 + (size_t)(mb * 128 + (c >> 2)) * K + k0 + (c & 3) * 8,
                       &As[(it * 256 + w * 64) * 8]);
            }
        }
        __syncthreads();
        f16x8 af[4], bf[4];
#pragma unroll
        for (int mt = 0; mt < 4; ++mt)
            af[mt] = *(const f16x8*)&As[(wm * 64 + mt * 16 + cl) * 32 + q * 8];
#pragma unroll
        for (int nt = 0; nt < 4; ++nt)
            bf[nt] = *(const f16x8*)&Bs[(wn * 64 + nt * 16 + cl) * 32 + q * 8];
#pragma unroll
        for (int mt = 0; mt < 4; ++mt)
#pragma unroll
            for (int nt = 0; nt < 4; ++nt)
                acc[mt][nt] = MFMA16(af[mt], bf[nt], acc[mt][nt]);
        __syncthreads();
    }
    float bv[4];
#pragma unroll
    for (int nt = 0; nt < 4; ++nt) bv[nt] = bias[nb * 128 + wn * 64 + nt * 16 + cl];
#pragma unroll
    for (int mt = 0; mt < 4; ++mt) {
#pragma unroll
        for (int nt = 0; nt < 4; ++nt) {
            size_t gr = (size_t)(mb * 128 + wm * 64 + mt * 16 + q * 4);
            int gc = nb * 128 + wn * 64 + nt * 16 + cl;
#pragma unroll
            for (int r = 0; r < 4; ++r) {
                float v = acc[mt][nt][r] + bv[nt];
                if (OUT_F16)
                    ((f16*)C_)[(gr + r) * N + gc] = (f16)v;
                else
                    ((float*)C_)[(gr + r) * N + gc] = v;
            }
        }
    }
}

// ---------------- segment-average partials ----------------
__global__ __launch_bounds__(256) void avg_kernel(const f16* __restrict__ X1h,
                                                  float* __restrict__ partial) {
    const int bn = blockIdx.x >> 2, rc = blockIdx.x & 3;
    const int tid = threadIdx.x;
    const f16* base = X1h + (size_t)bn * 262144 + (size_t)rc * 65536 + tid * 4;
    float s0 = 0.f, s1 = 0.f, s2 = 0.f, s3 = 0.f;
    for (int l = 0; l < 64; ++l) {
        f16x4 v = *(const f16x4*)(base + (size_t)l * 1024);
        s0 += (float)v[0]; s1 += (float)v[1]; s2 += (float)v[2]; s3 += (float)v[3];
    }
    const float sc = 1.f / 256.f;
    float4 o = make_float4(s0 * sc, s1 * sc, s2 * sc, s3 * sc);
    *(float4*)(partial + (size_t)(bn * 4 + rc) * 1024 + tid * 4) = o;
}

// ---------------- router ----------------
__global__ __launch_bounds__(64) void router_kernel(const float* __restrict__ partial,
                                                    const float* __restrict__ emb,
                                                    float* __restrict__ ew) {
    const int t = blockIdx.x;
    const int bn = t >> 3, h = t & 7;
    const int lane = threadIdx.x;
    float acc = 0.f;
    const float* p = partial + (size_t)bn * 4096 + h * 128;
    if (lane < 16) {
        for (int d = 0; d < 128; ++d) {
            float a = p[d] + p[d + 1024] + p[d + 2048] + p[d + 3072];
            acc = fmaf(a, emb[d * 16 + lane], acc);
        }
    }
    float m = acc;
#pragma unroll
    for (int o = 8; o; o >>= 1) m = fmaxf(m, __shfl_xor(m, o));
    float pr = __expf(acc - m);
    float s = pr;
#pragma unroll
    for (int o = 8; o; o >>= 1) s += __shfl_xor(s, o);
    if (lane < 16) ew[t * 16 + lane] = pr / s;
}

// ---------------- expert mixture ----------------
__global__ __launch_bounds__(256) void mix_kernel(const float* __restrict__ ew,
                                                  const float* __restrict__ FL,
                                                  const float* __restrict__ SL,
                                                  f16* __restrict__ m1h,
                                                  f16* __restrict__ m2h) {
    __shared__ float ews[4096];
    const int bid = blockIdx.x;
    const int which = bid >> 8, th = (bid >> 7) & 1, chunk = bid & 127;
    const float* src = which ? SL : FL;
    f16* dst = which ? m2h : m1h;
    const int tid = threadIdx.x;
    const int e0 = chunk * 512 + tid * 2;
    float2 fl[16];
#pragma unroll
    for (int e = 0; e < 16; ++e)
        fl[e] = *(const float2*)(src + (size_t)e * 65536 + e0);
    for (int i = tid; i < 4096; i += 256) ews[i] = ew[th * 4096 + i];
    __syncthreads();
#pragma unroll 1
    for (int tt = 0; tt < 256; ++tt) {
        float a0 = 0.f, a1 = 0.f;
#pragma unroll
        for (int e = 0; e < 16; ++e) {
            float wgt = ews[tt * 16 + e];
            a0 = fmaf(wgt, fl[e].x, a0);
            a1 = fmaf(wgt, fl[e].y, a1);
        }
        f16x2 h;
        h[0] = (f16)a0; h[1] = (f16)a1;
        *(f16x2*)(dst + (size_t)(th * 256 + tt) * 65536 + e0) = h;
    }
}

// ---------------- MLP v2: LDS-streamed weights ----------------
// Block = 4 waves, half-tile (128 l-rows x 128 d). X fragments global->reg once.
// Ws (32KB) alternates m1-chunk/m2-chunk via global_load_lds bursts; Hs (32KB)
// stages relu(h)^T per wave (wave-private rows, no cross-wave deps).
// Swizzle: store with column-perm on SOURCE (lc = pc ^ (row&7)), read granule
// ch = (k-granule) ^ (row&7) -> 2-way max bank conflict.
__device__ __forceinline__ void stage_w128(const f16* __restrict__ src, f16* lds,
                                           int w, int lane, int rowstride) {
#pragma unroll
    for (int it = 0; it < 8; ++it) {
        int cbase = it * 256 + w * 64;
        int c = cbase + lane;
        int row = c >> 4, pc = c & 15;
        int lc = pc ^ (row & 7);
        glds16(src + (size_t)row * rowstride + lc * 8, lds + cbase * 8);
    }
}

__global__ __launch_bounds__(256) void mlp_kernel(const f16* __restrict__ Xg,
                                                  const f16* __restrict__ m1h,
                                                  const f16* __restrict__ m2h,
                                                  f16* __restrict__ Yg) {
    __shared__ f16 Hs[128 * 128];
    __shared__ f16 Ws[128 * 128];
    const int bid = blockIdx.x;
    const int t = bid >> 1, lh = bid & 1;
    const int n = (t >> 3) & 15;
    const int tm = (n > 0) ? (t - 8) : t;
    const int tid = threadIdx.x;
    const int lane = tid & 63, w = tid >> 6;
    const int q = lane >> 4, cl = lane & 15;
    const int l0 = w * 32;

    const f16* Xsrc = Xg + (size_t)t * 32768 + lh * 16384;
    const f16* m1b = m1h + (size_t)tm * 65536;
    const f16* m2b = m2h + (size_t)tm * 65536;

    // X fragments: direct global->reg, invariant across ic chunks (16 VGPRs)
    f16x8 xf[2][4];
#pragma unroll
    for (int lt = 0; lt < 2; ++lt) {
        int l = l0 + lt * 16 + cl;
#pragma unroll
        for (int ks = 0; ks < 4; ++ks)
            xf[lt][ks] = *(const f16x8*)(Xsrc + (size_t)l * 128 + ks * 32 + q * 8);
    }
    stage_w128(m1b, Ws, w, lane, 128);  // m1 chunk 0 in flight with xf loads
    __syncthreads();                    // drains vmcnt(0): xf + m1[0] ready

    f32x4 acc2[2][8] = {};
#pragma unroll 1
    for (int ic = 0; ic < 4; ++ic) {
        // ---- stage1: h^T[i, l] over i-chunk, Ws = m1[ic] ----
#pragma unroll
        for (int it = 0; it < 8; ++it) {
            f16x8 af[4];
#pragma unroll
            for (int ks = 0; ks < 4; ++ks) {
                int r = it * 16 + cl;
                int ch = (ks * 4 + q) ^ (r & 7);
                af[ks] = *(const f16x8*)&Ws[r * 128 + ch * 8];
            }
            f32x4 a1[2] = {};
#pragma unroll
            for (int ks = 0; ks < 4; ++ks)
#pragma unroll
                for (int lt = 0; lt < 2; ++lt)
                    a1[lt] = MFMA16(af[ks], xf[lt][ks], a1[lt]);
            int ibase = it * 16 + q * 4;
            int ch = ibase >> 3;
            int sub = (q & 1) * 8;
#pragma unroll
            for (int lt = 0; lt < 2; ++lt) {
                int l = l0 + lt * 16 + cl;
                f16x4 hv;
                hv[0] = (f16)fmaxf(a1[lt][0], 0.f);
                hv[1] = (f16)fmaxf(a1[lt][1], 0.f);
                hv[2] = (f16)fmaxf(a1[lt][2], 0.f);
                hv[3] = (f16)fmaxf(a1[lt][3], 0.f);
                *(f16x4*)((char*)Hs + (size_t)l * 256 + ((ch ^ (l & 7)) << 4) + sub) = hv;
            }
        }
        __syncthreads();                       // all waves done reading Ws (m1)
        stage_w128(m2b + ic * 128, Ws, w, lane, 512);
        __syncthreads();                       // m2[ic] ready

        // ---- stage2: acc2 += h @ m2[ic]^T ----
        f16x8 hf[2][4];
#pragma unroll
        for (int lt = 0; lt < 2; ++lt) {
            int l = l0 + lt * 16 + cl;
#pragma unroll
            for (int ks = 0; ks < 4; ++ks) {
                int ch = (ks * 4 + q) ^ (l & 7);
                hf[lt][ks] = *(const f16x8*)&Hs[l * 128 + ch * 8];
            }
        }
#pragma unroll
        for (int nt = 0; nt < 8; ++nt) {
            f16x8 bf[4];
#pragma unroll
            for (int ks = 0; ks < 4; ++ks) {
                int r = nt * 16 + cl;
                int ch = (ks * 4 + q) ^ (r & 7);
                bf[ks] = *(const f16x8*)&Ws[r * 128 + ch * 8];
            }
#pragma unroll
            for (int lt = 0; lt < 2; ++lt)
#pragma unroll
                for (int ks = 0; ks < 4; ++ks)
                    acc2[lt][nt] = MFMA16(hf[lt][ks], bf[ks], acc2[lt][nt]);
        }
        __syncthreads();                       // Ws (m2) consumed
        if (ic < 3) {
            stage_w128(m1b + (size_t)(ic + 1) * 16384, Ws, w, lane, 128);
            __syncthreads();                   // m1[ic+1] ready
        }
    }
    // epilogue: in-place write (this block's X already consumed into xf)
    f16* Yb = Yg + (size_t)t * 32768 + lh * 16384;
#pragma unroll
    for (int lt = 0; lt < 2; ++lt) {
#pragma unroll
        for (int nt = 0; nt < 8; ++nt) {
            int lr = l0 + lt * 16 + q * 4;
            int d = nt * 16 + cl;
#pragma unroll
            for (int r = 0; r < 4; ++r)
                Yb[(size_t)(lr + r) * 128 + d] = (f16)acc2[lt][nt][r];
        }
    }
}

extern "C" void kernel_launch(void* const* d_in, const int* in_sizes, int n_in,
                              void* d_out, int out_size, void* d_ws, size_t ws_size,
                              hipStream_t stream) {
    const float* x    = (const float*)d_in[0];
    const float* W_mh = (const float*)d_in[1];
    const float* b_mh = (const float*)d_in[2];
    const float* W_mg = (const float*)d_in[3];
    const float* b_mg = (const float*)d_in[4];
    const float* emb  = (const float*)d_in[5];
    const float* FL   = (const float*)d_in[6];
    const float* SL   = (const float*)d_in[7];

    char* ws = (char*)d_ws;
    f16*   X1h  = (f16*)(ws + 0);
    f16*   m1h  = (f16*)(ws + 33554432);
    f16*   m2h  = (f16*)(ws + 100663296);
    f16*   Wmhh = (f16*)(ws + 167772160);
    f16*   Wmgh = (f16*)(ws + 169869312);
    float* part = (float*)(ws + 171966464);
    float* ew   = (float*)(ws + 173015040);

    cvt_kernel<<<512, 256, 0, stream>>>(W_mh, Wmhh, 1048576);
    cvt_kernel<<<512, 256, 0, stream>>>(W_mg, Wmgh, 1048576);
    gemm_bt_kernel<true, true><<<1024, 256, 0, stream>>>(x, Wmhh, b_mh, X1h,
                                                         16384, 1024, 1024);
    avg_kernel<<<256, 256, 0, stream>>>(X1h, part);
    router_kernel<<<512, 64, 0, stream>>>(part, emb, ew);
    mix_kernel<<<512, 256, 0, stream>>>(ew, FL, SL, m1h, m2h);
    mlp_kernel<<<1024, 256, 0, stream>>>(X1h, m1h, m2h, X1h);
    gemm_bt_kernel<false, false><<<1024, 256, 0, stream>>>(X1h, Wmgh, b_mg, d_out,
                                                           16384, 1024, 1024);
}